// Round 8
// baseline (1017.356 us; speedup 1.0000x reference)
//
#include <hip/hip_runtime.h>
#include <hip/hip_cooperative_groups.h>

namespace cg = cooperative_groups;

#define DEV __device__ __forceinline__

constexpr int Bc = 2, Tc = 128, Dc = 256, Lc = 8, Hc = 4, DH = 64, Fc = 2048;
constexpr float EPS = 1e-5f, SCALE = 0.125f;  // 1/sqrt(64)
constexpr int NROWS = Bc * Tc * Lc;           // 2048 candidate rows
constexpr int SLAB = NROWS * Dc;              // 524288 floats

// ---- workspace layout (float offsets) ----
constexpr int OFF_K     = 0;                        // B*T*D frame keys
constexpr int OFF_VWOH  = OFF_K + Bc * Tc * Dc;     // B*T*H*D per-head v@Wo partials
constexpr int OFF_QCLS  = OFF_VWOH + Bc * Tc * Hc * Dc;
constexpr int OFF_KCLS  = OFF_QCLS + Dc;
constexpr int OFF_VWOHC = OFF_KCLS + Dc;            // H*D
constexpr int OFF_X0    = OFF_VWOHC + Hc * Dc;      // B*T*L*D x0; P3 overwrites as ENC
constexpr int OFF_ENC   = OFF_X0;
constexpr int OFF_H2    = OFF_X0 + SLAB;            // B*T*L*D ln2(x0)
constexpr int OFF_UP    = OFF_H2 + SLAB;            // 2*SLAB FFN half sums
constexpr int OFF_Z     = OFF_UP + 2 * SLAB;        // B*T*L eoc logits
constexpr int OFF_LST   = OFF_Z + NROWS;            // B*T ints chosen lengths
// total ~2.43M floats ~= 9.7 MB

DEV int imin(int a, int b) { return a < b ? a : b; }
DEV float4 f4add(float4 a, float4 b) {
  float4 r; r.x = a.x + b.x; r.y = a.y + b.y; r.z = a.z + b.z; r.w = a.w + b.w; return r;
}

// ONE cooperative kernel: 256 blocks x 512 threads, 1 block/CU co-resident.
// P0 prep -> P1 attn -> P2 FFN(16 rows x F-half) -> P3 enc+z+select -> P4 emit,
// separated by grid.sync(). Block->work mapping changes per phase.
__global__ __launch_bounds__(512) void k_mega(
    const float* __restrict__ frames, const float* __restrict__ cls,
    const float* __restrict__ Wq, const float* __restrict__ bq,
    const float* __restrict__ Wk, const float* __restrict__ bk,
    const float* __restrict__ Wv, const float* __restrict__ bv,
    const float* __restrict__ Wo, const float* __restrict__ bo,
    const float* __restrict__ g1, const float* __restrict__ b1,
    const float* __restrict__ g2, const float* __restrict__ b2,
    const float* __restrict__ W1, const float* __restrict__ b1f,
    const float* __restrict__ W2, const float* __restrict__ b2f,
    const float* __restrict__ We1, const float* __restrict__ be1,
    const float* __restrict__ We2, const float* __restrict__ be2,
    float* __restrict__ ws, float* __restrict__ out) {
  cg::grid_group gridg = cg::this_grid();
  const int blk = blockIdx.x;
  const int tid = threadIdx.x;
  const int lane = tid & 63;
  const int wv = tid >> 6;

  __shared__ __align__(16) float ts[16][1024];   // 64KB; P2 T-buffer, then redb[4][16][256]
  __shared__ __align__(16) float h2s[16][256];   // 16KB
  __shared__ __align__(16) float encs[8][256];   // 8KB
  __shared__ float hsm[256];
  __shared__ float vsm[256];
  __shared__ __align__(16) float red4[4];
  __shared__ float sv[Hc][Lc + 1];
  __shared__ float aP[Lc][Hc][Lc + 1];
  __shared__ __align__(16) float redA[Lc][4];
  __shared__ __align__(16) float redB[Lc][4];
  __shared__ __align__(16) float zred[8][4];
  __shared__ float zs[8];
  __shared__ int lst[Tc];
  __shared__ int path[Tc];
  __shared__ int cnt_s;

  // ================= P0: prep (row = blk; block 0 also does cls row) ==========
  for (int r = blk; r <= Bc * Tc; r += 256) {
    const int d = tid & 255;
    const int kg = tid >> 8;  // 0: k-proj, 1: v-proj
    float x = 0.f;
    if (tid < 256) x = (r < Bc * Tc) ? frames[r * Dc + d] : cls[d];
    float p = x;
#pragma unroll
    for (int off = 32; off; off >>= 1) p += __shfl_down(p, off, 64);
    if (tid < 256 && lane == 0) red4[wv] = p;
    __syncthreads();
    const float mean0 = (((red4[0] + red4[1]) + red4[2]) + red4[3]) * (1.f / Dc);
    const float cv = x - mean0;
    p = cv * cv;
#pragma unroll
    for (int off = 32; off; off >>= 1) p += __shfl_down(p, off, 64);
    __syncthreads();
    if (tid < 256 && lane == 0) red4[wv] = p;
    __syncthreads();
    const float var = (((red4[0] + red4[1]) + red4[2]) + red4[3]) * (1.f / Dc);
    if (tid < 256) hsm[d] = cv * (1.f / sqrtf(var + EPS)) * g1[d] + b1[d];
    __syncthreads();
    {
      const float* W = kg ? Wv : Wk;
      float a = kg ? bv[d] : bk[d];
      for (int c2 = 0; c2 < Dc; ++c2) a = fmaf(hsm[c2], W[c2 * Dc + d], a);
      if (kg == 0) {
        if (r < Bc * Tc) ws[OFF_K + r * Dc + d] = a;
        else             ws[OFF_KCLS + d] = a;
      } else {
        vsm[d] = a;
      }
    }
    __syncthreads();
    if (tid < 256) {
#pragma unroll
      for (int hh = 0; hh < Hc; ++hh) {
        float acc = 0.f;
        for (int c2 = 0; c2 < DH; ++c2)
          acc = fmaf(vsm[hh * DH + c2], Wo[(hh * DH + c2) * Dc + d], acc);
        if (r < Bc * Tc) ws[OFF_VWOH + r * (Hc * Dc) + hh * Dc + d] = acc;
        else             ws[OFF_VWOHC + hh * Dc + d] = acc;
      }
    } else if (r == Bc * Tc) {
      float qa = bq[d];
      for (int c2 = 0; c2 < Dc; ++c2) qa = fmaf(hsm[c2], Wq[c2 * Dc + d], qa);
      ws[OFF_QCLS + d] = qa;
    }
    __syncthreads();
  }
  __threadfence();
  gridg.sync();
  __threadfence();

  // ================= P1: attn per (b,i) = blk; h2/x0 -> global ================
  {
    const int wg = blk;
    const int i = wg & (Tc - 1);
    const int lmax = imin(Tc - i, Lc);
    if (tid < 256) {
      const int hh = tid >> 6;
      const float qv = ws[OFF_QCLS + hh * DH + lane];
      for (int j = 0; j <= Lc; ++j) {
        float p = 0.f;
        if (j == 0) p = qv * ws[OFF_KCLS + hh * DH + lane];
        else if (j - 1 < lmax) p = qv * ws[OFF_K + (wg + j - 1) * Dc + hh * DH + lane];
#pragma unroll
        for (int off = 32; off; off >>= 1) p += __shfl_down(p, off, 64);
        if (lane == 0) sv[hh][j] = p * SCALE;
      }
    }
    __syncthreads();
    if (tid < Lc * Hc) {
      const int l = (tid >> 2) + 1, h4 = tid & 3;
      if (l <= lmax) {
        float mx = -1e30f;
        for (int j = 0; j <= l; ++j) mx = fmaxf(mx, sv[h4][j]);
        float den = 0.f;
        for (int j = 0; j <= l; ++j) den += expf(sv[h4][j] - mx);
        const float inv = 1.f / den;
        for (int j = 0; j <= l; ++j) aP[l - 1][h4][j] = expf(sv[h4][j] - mx) * inv;
      }
    }
    __syncthreads();
    float x0v[Lc];
    if (tid < 256) {
      const int d = tid;
      const float base = cls[d] + bo[d];
#pragma unroll
      for (int l = 0; l < Lc; ++l) x0v[l] = base;
      for (int j = 0; j <= lmax; ++j) {
        const float* vwp = (j == 0) ? (ws + OFF_VWOHC)
                                    : (ws + OFF_VWOH + (wg + j - 1) * (Hc * Dc));
        for (int h4 = 0; h4 < Hc; ++h4) {
          const float w = vwp[h4 * Dc + d];
          const int lstart = (j == 0) ? 1 : j;
          for (int l = lstart; l <= lmax; ++l) x0v[l - 1] = fmaf(aP[l - 1][h4][j], w, x0v[l - 1]);
        }
      }
#pragma unroll
      for (int l = 0; l < Lc; ++l) {
        float p = x0v[l];
#pragma unroll
        for (int off = 32; off; off >>= 1) p += __shfl_down(p, off, 64);
        if (lane == 0) redA[l][tid >> 6] = p;
      }
    }
    __syncthreads();
    float mean[Lc];
    if (tid < 256) {
#pragma unroll
      for (int l = 0; l < Lc; ++l) {
        const float4 s4 = *(const float4*)redA[l];
        mean[l] = (s4.x + s4.y + s4.z + s4.w) * (1.f / Dc);
      }
#pragma unroll
      for (int l = 0; l < Lc; ++l) {
        const float cv2 = x0v[l] - mean[l];
        float p = cv2 * cv2;
#pragma unroll
        for (int off = 32; off; off >>= 1) p += __shfl_down(p, off, 64);
        if (lane == 0) redB[l][tid >> 6] = p;
      }
    }
    __syncthreads();
    if (tid < 256) {
      const int d = tid;
      const float g2d = g2[d], b2d = b2[d];
      for (int l = 1; l <= lmax; ++l) {
        const float4 s4 = *(const float4*)redB[l - 1];
        const float var = (s4.x + s4.y + s4.z + s4.w) * (1.f / Dc);
        const float rstd = 1.f / sqrtf(var + EPS);
        ws[OFF_H2 + (wg * Lc + l - 1) * Dc + d] = (x0v[l - 1] - mean[l - 1]) * rstd * g2d + b2d;
        ws[OFF_X0 + (wg * Lc + l - 1) * Dc + d] = x0v[l - 1];
      }
      for (int l = lmax + 1; l <= Lc; ++l) {
        ws[OFF_H2 + (wg * Lc + l - 1) * Dc + d] = 0.f;
        ws[OFF_X0 + (wg * Lc + l - 1) * Dc + d] = 0.f;
      }
    }
  }
  __threadfence();
  gridg.sync();
  __threadfence();

  // ================= P2: FFN, 16 rows x F-half per block =====================
  {
    const int mtile = blk >> 1;
    const int half = blk & 1;
    const int r0 = mtile * 16;
    {
      const float4* src = (const float4*)(ws + OFF_H2 + r0 * Dc);
      float4* dst = (float4*)&h2s[0][0];
      dst[tid] = src[tid];
      dst[tid + 512] = src[tid + 512];
    }
    __syncthreads();

    // phase 1: T = relu(h2 @ W1[:,half] + b1f); thread owns 2 f-cols; no barrier
    const int fl = tid * 2;
    const int fg = half * 1024 + fl;
    float t[16][2];
    {
      const float2 bb = *(const float2*)&b1f[fg];
#pragma unroll
      for (int r = 0; r < 16; ++r) { t[r][0] = bb.x; t[r][1] = bb.y; }
    }
    for (int c = 0; c < Dc; c += 4) {
      float2 w1v[4];
#pragma unroll
      for (int k = 0; k < 4; ++k) w1v[k] = *(const float2*)&W1[(c + k) * Fc + fg];
#pragma unroll
      for (int r = 0; r < 16; ++r) {
        const float4 h = *(const float4*)&h2s[r][c];
        const float hv[4] = {h.x, h.y, h.z, h.w};
#pragma unroll
        for (int k = 0; k < 4; ++k) {
          t[r][0] = fmaf(hv[k], w1v[k].x, t[r][0]);
          t[r][1] = fmaf(hv[k], w1v[k].y, t[r][1]);
        }
      }
    }
#pragma unroll
    for (int r = 0; r < 16; ++r) {
      float2 v; v.x = fmaxf(t[r][0], 0.f); v.y = fmaxf(t[r][1], 0.f);
      *(float2*)&ts[r][fl] = v;
    }
    __syncthreads();

    // phase 2: wave wv owns k-slice of 128 within the half
    const int d4 = lane * 4;
    const int ks = wv * 128;
    float u[16][4];
#pragma unroll
    for (int r = 0; r < 16; ++r) { u[r][0] = 0.f; u[r][1] = 0.f; u[r][2] = 0.f; u[r][3] = 0.f; }
    for (int kk = 0; kk < 128; kk += 4) {
      float4 w2v[4];
#pragma unroll
      for (int k = 0; k < 4; ++k)
        w2v[k] = *(const float4*)&W2[(half * 1024 + ks + kk + k) * Dc + d4];
#pragma unroll
      for (int r = 0; r < 16; ++r) {
        const float4 h = *(const float4*)&ts[r][ks + kk];
        const float hv[4] = {h.x, h.y, h.z, h.w};
#pragma unroll
        for (int k = 0; k < 4; ++k) {
          u[r][0] = fmaf(hv[k], w2v[k].x, u[r][0]);
          u[r][1] = fmaf(hv[k], w2v[k].y, u[r][1]);
          u[r][2] = fmaf(hv[k], w2v[k].z, u[r][2]);
          u[r][3] = fmaf(hv[k], w2v[k].w, u[r][3]);
        }
      }
    }
    __syncthreads();  // all ts reads done before aliasing as redb

    // sequential 8-partial reduce (w0..w7), two rounds through 64KB redb
    float4* redb4 = (float4*)&ts[0][0];  // [4][16][64] float4
    if (wv < 4) {
#pragma unroll
      for (int r = 0; r < 16; ++r) {
        float4 v; v.x = u[r][0]; v.y = u[r][1]; v.z = u[r][2]; v.w = u[r][3];
        redb4[(wv * 16 + r) * 64 + lane] = v;
      }
    }
    __syncthreads();
    float4 sA, sB;
    {
      const int id0 = tid, id1 = tid + 512;
      sA = redb4[id0];
      sA = f4add(sA, redb4[1024 + id0]); sA = f4add(sA, redb4[2048 + id0]); sA = f4add(sA, redb4[3072 + id0]);
      sB = redb4[id1];
      sB = f4add(sB, redb4[1024 + id1]); sB = f4add(sB, redb4[2048 + id1]); sB = f4add(sB, redb4[3072 + id1]);
    }
    __syncthreads();
    if (wv >= 4) {
#pragma unroll
      for (int r = 0; r < 16; ++r) {
        float4 v; v.x = u[r][0]; v.y = u[r][1]; v.z = u[r][2]; v.w = u[r][3];
        redb4[((wv - 4) * 16 + r) * 64 + lane] = v;
      }
    }
    __syncthreads();
    {
      const int id0 = tid, id1 = tid + 512;
      sA = f4add(sA, redb4[id0]);
      sA = f4add(sA, redb4[1024 + id0]); sA = f4add(sA, redb4[2048 + id0]); sA = f4add(sA, redb4[3072 + id0]);
      sB = f4add(sB, redb4[id1]);
      sB = f4add(sB, redb4[1024 + id1]); sB = f4add(sB, redb4[2048 + id1]); sB = f4add(sB, redb4[3072 + id1]);
      float4* up4 = (float4*)(ws + OFF_UP + half * SLAB + r0 * Dc);
      up4[id0] = sA;
      up4[id1] = sB;
    }
  }
  __threadfence();
  gridg.sync();
  __threadfence();

  // ================= P3: enc + z + select per (b,i) = blk ====================
  {
    const int wg = blk;
    const int i = wg & (Tc - 1);
    {
      const int row = tid >> 6;
      const int dd = (tid & 63) * 4;
      const int g4 = wg * 512 + tid;  // float4 index into [NROWS][Dc]
      const float4 x0 = ((const float4*)(ws + OFF_X0))[g4];
      const float4 u0 = ((const float4*)(ws + OFF_UP))[g4];
      const float4 u1 = ((const float4*)(ws + OFF_UP + SLAB))[g4];
      const float4 bb = *(const float4*)&b2f[dd];
      float4 e;
      e.x = (x0.x + (u0.x + u1.x)) + bb.x;
      e.y = (x0.y + (u0.y + u1.y)) + bb.y;
      e.z = (x0.z + (u0.z + u1.z)) + bb.z;
      e.w = (x0.w + (u0.w + u1.w)) + bb.w;
      ((float4*)(ws + OFF_ENC))[g4] = e;
      *(float4*)&encs[row][dd] = e;
    }
    __syncthreads();
    {
      const int f = tid & 255;
      const int rh = tid >> 8;
      float g[4];
      const float be1f = be1[f];
#pragma unroll
      for (int rr = 0; rr < 4; ++rr) g[rr] = be1f;
      for (int c = 0; c < Dc; ++c) {
        const float w = We1[c * Dc + f];
#pragma unroll
        for (int rr = 0; rr < 4; ++rr) g[rr] = fmaf(encs[rh * 4 + rr][c], w, g[rr]);
      }
      const float w2 = We2[f];
#pragma unroll
      for (int rr = 0; rr < 4; ++rr) {
        float p = fmaxf(g[rr], 0.f) * w2;
#pragma unroll
        for (int off = 32; off; off >>= 1) p += __shfl_down(p, off, 64);
        if (lane == 0) zred[wv][rr] = p;
      }
    }
    __syncthreads();
    if (tid < 8) {
      const int r = tid;
      const int wb = (r < 4) ? 0 : 4;
      const int rl = r & 3;
      const float z = ((zred[wb + 0][rl] + zred[wb + 1][rl]) + zred[wb + 2][rl]) +
                      zred[wb + 3][rl] + be2[0];
      zs[r] = z;
      ws[OFF_Z + wg * Lc + r] = z;
    }
    __syncthreads();
    if (tid == 0) {
      const int lmax = imin(Tc - i, Lc);
      int ls = lmax;
      for (int l = 1; l <= lmax; ++l) {
        if (zs[l - 1] > 0.f) { ls = l; break; }
      }
      ((int*)(ws + OFF_LST))[wg] = ls;
    }
  }
  __threadfence();
  gridg.sync();
  __threadfence();

  // ================= P4: emit (blocks 0..1) ===================================
  if (blk < Bc) {
    const int b = blk;
    const int* lsrc = (const int*)(ws + OFF_LST);
    if (tid < Tc) lst[tid] = lsrc[b * Tc + tid];
    __syncthreads();
    if (tid < 64) {
      const int a0 = lst[tid], a1 = lst[64 + tid];
      int cur = 0, s = 0;
      while (cur < Tc) {
        const int l = (cur < 64) ? __shfl(a0, cur, 64) : __shfl(a1, cur - 64, 64);
        if (tid == 0) path[s] = cur * Lc + l - 1;
        ++s;
        cur += l;
      }
      if (tid == 0) cnt_s = s;
    }
    __syncthreads();
    const int c = cnt_s;
    if (tid < 256) {
      for (int s0 = 0; s0 < Tc; s0 += 8) {
        float v[8];
#pragma unroll
        for (int k = 0; k < 8; ++k) {
          const int s = s0 + k;
          v[k] = (s < c) ? ws[OFF_ENC + (b * Tc * Lc + path[s]) * Dc + tid] : 0.f;
        }
#pragma unroll
        for (int k = 0; k < 8; ++k) out[(b * Tc + s0 + k) * Dc + tid] = v[k];
      }
    }
    if (tid == 0) out[Bc * Tc * Dc + b] = (float)c;
  }
}

extern "C" void kernel_launch(void* const* d_in, const int* in_sizes, int n_in,
                              void* d_out, int out_size, void* d_ws, size_t ws_size,
                              hipStream_t stream) {
  const float* frames = (const float*)d_in[0];
  const float* cls    = (const float*)d_in[1];
  const float* Wq     = (const float*)d_in[2];
  const float* bq     = (const float*)d_in[3];
  const float* Wk     = (const float*)d_in[4];
  const float* bk     = (const float*)d_in[5];
  const float* Wv     = (const float*)d_in[6];
  const float* bv     = (const float*)d_in[7];
  const float* Wo     = (const float*)d_in[8];
  const float* bo     = (const float*)d_in[9];
  const float* g1     = (const float*)d_in[10];
  const float* b1     = (const float*)d_in[11];
  const float* g2     = (const float*)d_in[12];
  const float* b2     = (const float*)d_in[13];
  const float* W1     = (const float*)d_in[14];
  const float* b1f    = (const float*)d_in[15];
  const float* W2     = (const float*)d_in[16];
  const float* b2f    = (const float*)d_in[17];
  const float* We1    = (const float*)d_in[18];
  const float* be1    = (const float*)d_in[19];
  const float* We2    = (const float*)d_in[20];
  const float* be2    = (const float*)d_in[21];
  float* ws = (float*)d_ws;
  float* out = (float*)d_out;

  void* args[] = {
      (void*)&frames, (void*)&cls, (void*)&Wq, (void*)&bq, (void*)&Wk, (void*)&bk,
      (void*)&Wv, (void*)&bv, (void*)&Wo, (void*)&bo, (void*)&g1, (void*)&b1,
      (void*)&g2, (void*)&b2, (void*)&W1, (void*)&b1f, (void*)&W2, (void*)&b2f,
      (void*)&We1, (void*)&be1, (void*)&We2, (void*)&be2, (void*)&ws, (void*)&out};
  hipLaunchCooperativeKernel((void*)k_mega, dim3(256), dim3(512), args, 0, stream);
}

// Round 9
// 248.597 us; speedup vs baseline: 4.0924x; 4.0924x over previous
//
#include <hip/hip_runtime.h>

#define DEV __device__ __forceinline__

constexpr int Bc = 2, Tc = 128, Dc = 256, Lc = 8, Hc = 4, DH = 64, Fc = 2048;
constexpr float EPS = 1e-5f, SCALE = 0.125f;  // 1/sqrt(64)
constexpr int NROWS = Bc * Tc * Lc;           // 2048 candidate rows
constexpr int SLAB = NROWS * Dc;              // 524288 floats

// ---- workspace layout (float offsets) ----
constexpr int OFF_K     = 0;                        // B*T*D frame keys
constexpr int OFF_VWOH  = OFF_K + Bc * Tc * Dc;     // B*T*H*D per-head v@Wo partials
constexpr int OFF_QCLS  = OFF_VWOH + Bc * Tc * Hc * Dc;
constexpr int OFF_KCLS  = OFF_QCLS + Dc;
constexpr int OFF_VWOHC = OFF_KCLS + Dc;            // H*D
constexpr int OFF_X0    = OFF_VWOHC + Hc * Dc;      // B*T*L*D x0; k_encz overwrites as ENC
constexpr int OFF_ENC   = OFF_X0;
constexpr int OFF_LNP   = OFF_X0 + SLAB;            // B*T*L*2 per-row (mean, rstd)
constexpr int OFF_UP    = OFF_LNP + NROWS * 2;      // 4*SLAB FFN quarter partials
constexpr int OFF_Z     = OFF_UP + 4 * SLAB;        // B*T*L eoc logits
constexpr int OFF_LST   = OFF_Z + NROWS;            // B*T ints chosen lengths
// total ~3.2M floats ~= 12.8 MB

DEV int imin(int a, int b) { return a < b ? a : b; }
DEV float4 f4add(float4 a, float4 b) {
  float4 r; r.x = a.x + b.x; r.y = a.y + b.y; r.z = a.z + b.z; r.w = a.w + b.w; return r;
}

// block = 256 threads (4 waves). red must be shared float[4].
DEV float blockReduceSum(float v, float* red) {
#pragma unroll
  for (int off = 32; off; off >>= 1) v += __shfl_down(v, off, 64);
  const int lane = threadIdx.x & 63;
  const int w = threadIdx.x >> 6;
  __syncthreads();  // protect red from previous use
  if (lane == 0) red[w] = v;
  __syncthreads();
  return red[0] + red[1] + red[2] + red[3];
}

// ---- K1: one row per block. LN1 + k/v projections + per-head v@Wo; q for CLS row. ----
__global__ __launch_bounds__(256) void k_prep(
    const float* __restrict__ frames, const float* __restrict__ cls,
    const float* __restrict__ Wq, const float* __restrict__ bq,
    const float* __restrict__ Wk, const float* __restrict__ bk,
    const float* __restrict__ Wv, const float* __restrict__ bv,
    const float* __restrict__ Wo,
    const float* __restrict__ g1, const float* __restrict__ b1,
    float* __restrict__ ws) {
  __shared__ float hsm[Dc];
  __shared__ float vsm[Dc];
  __shared__ float red[4];
  const int d = threadIdx.x;
  const int r = blockIdx.x;  // 0..B*T-1 frames, B*T = cls

  const float x = (r < Bc * Tc) ? frames[r * Dc + d] : cls[d];
  const float s = blockReduceSum(x, red);
  const float m = s * (1.0f / Dc);
  const float c = x - m;
  const float var = blockReduceSum(c * c, red) * (1.0f / Dc);
  hsm[d] = c * (1.0f / sqrtf(var + EPS)) * g1[d] + b1[d];
  __syncthreads();

  float ka = bk[d], va = bv[d];
  for (int c2 = 0; c2 < Dc; ++c2) {
    const float h = hsm[c2];
    ka = fmaf(h, Wk[c2 * Dc + d], ka);
    va = fmaf(h, Wv[c2 * Dc + d], va);
  }
  if (r < Bc * Tc) ws[OFF_K + r * Dc + d] = ka;
  else             ws[OFF_KCLS + d] = ka;
  vsm[d] = va;
  __syncthreads();

#pragma unroll
  for (int hh = 0; hh < Hc; ++hh) {
    float acc = 0.f;
    for (int c2 = 0; c2 < DH; ++c2)
      acc = fmaf(vsm[hh * DH + c2], Wo[(hh * DH + c2) * Dc + d], acc);
    if (r < Bc * Tc) ws[OFF_VWOH + r * (Hc * Dc) + hh * Dc + d] = acc;
    else             ws[OFF_VWOHC + hh * Dc + d] = acc;
  }
  if (r == Bc * Tc) {
    float qa = bq[d];
    for (int c2 = 0; c2 < Dc; ++c2) qa = fmaf(hsm[c2], Wq[c2 * Dc + d], qa);
    ws[OFF_QCLS + d] = qa;
  }
}

// ---- K2: attn per (b,i): scores + softmax + x0 + LN stats. Writes X0 + (mean,rstd). ----
__global__ __launch_bounds__(256) void k_attn(
    const float* __restrict__ cls, const float* __restrict__ bo,
    float* __restrict__ ws) {
  const int wg = blockIdx.x;  // b*T + i
  const int i = wg & (Tc - 1);
  const int tid = threadIdx.x;
  const int wv = tid >> 6, lane = tid & 63;
  const int lmax = imin(Tc - i, Lc);
  __shared__ float sv[Hc][Lc + 1];
  __shared__ float aP[Lc][Hc][Lc + 1];
  __shared__ __align__(16) float redA[Lc][4];
  __shared__ __align__(16) float redB[Lc][4];

  // scores: wave = head
  {
    const float qv = ws[OFF_QCLS + wv * DH + lane];
    for (int j = 0; j <= Lc; ++j) {
      float p = 0.f;
      if (j == 0) p = qv * ws[OFF_KCLS + wv * DH + lane];
      else if (j - 1 < lmax) p = qv * ws[OFF_K + (wg + j - 1) * Dc + wv * DH + lane];
#pragma unroll
      for (int off = 32; off; off >>= 1) p += __shfl_down(p, off, 64);
      if (lane == 0) sv[wv][j] = p * SCALE;
    }
  }
  __syncthreads();

  if (tid < Lc * Hc) {
    const int l = (tid >> 2) + 1, h4 = tid & 3;
    if (l <= lmax) {
      float mx = -1e30f;
      for (int j = 0; j <= l; ++j) mx = fmaxf(mx, sv[h4][j]);
      float den = 0.f;
      for (int j = 0; j <= l; ++j) den += expf(sv[h4][j] - mx);
      const float inv = 1.f / den;
      for (int j = 0; j <= l; ++j) aP[l - 1][h4][j] = expf(sv[h4][j] - mx) * inv;
    }
  }
  __syncthreads();

  const int d = tid;
  float x0v[Lc];
  {
    const float base = cls[d] + bo[d];
#pragma unroll
    for (int l = 0; l < Lc; ++l) x0v[l] = base;
    for (int j = 0; j <= lmax; ++j) {
      const float* vwp = (j == 0) ? (ws + OFF_VWOHC)
                                  : (ws + OFF_VWOH + (wg + j - 1) * (Hc * Dc));
      for (int h4 = 0; h4 < Hc; ++h4) {
        const float w = vwp[h4 * Dc + d];
        const int lstart = (j == 0) ? 1 : j;
        for (int l = lstart; l <= lmax; ++l) x0v[l - 1] = fmaf(aP[l - 1][h4][j], w, x0v[l - 1]);
      }
    }
  }
#pragma unroll
  for (int l = 0; l < Lc; ++l) {
    float p = x0v[l];
#pragma unroll
    for (int off = 32; off; off >>= 1) p += __shfl_down(p, off, 64);
    if (lane == 0) redA[l][wv] = p;
  }
  __syncthreads();
  float mean[Lc];
#pragma unroll
  for (int l = 0; l < Lc; ++l) {
    const float4 s4 = *(const float4*)redA[l];
    mean[l] = (s4.x + s4.y + s4.z + s4.w) * (1.f / Dc);
  }
#pragma unroll
  for (int l = 0; l < Lc; ++l) {
    const float cv = x0v[l] - mean[l];
    float p = cv * cv;
#pragma unroll
    for (int off = 32; off; off >>= 1) p += __shfl_down(p, off, 64);
    if (lane == 0) redB[l][wv] = p;
  }
  __syncthreads();

  for (int l = 1; l <= Lc; ++l) {
    const int rowc = wg * Lc + l - 1;
    ws[OFF_X0 + rowc * Dc + d] = (l <= lmax) ? x0v[l - 1] : 0.f;
    if (d == 0) {
      if (l <= lmax) {
        const float4 s4 = *(const float4*)redB[l - 1];
        const float var = (s4.x + s4.y + s4.z + s4.w) * (1.f / Dc);
        ws[OFF_LNP + rowc * 2 + 0] = mean[l - 1];
        ws[OFF_LNP + rowc * 2 + 1] = 1.f / sqrtf(var + EPS);
      } else {
        ws[OFF_LNP + rowc * 2 + 0] = 0.f;
        ws[OFF_LNP + rowc * 2 + 1] = 0.f;  // padded row: h2 = b2, unused downstream
      }
    }
  }
}

// ---- K3: FFN quarter. 512 blocks = 128 row-tiles(16) x 4 F-quarters(512).
// 256 threads, LDS 48KB -> 3 blocks/CU. Phase 1: wave-row-split (waves 0-1 rows
// 0-7, waves 2-3 rows 8-15), thread owns 4 f-cols (float4 W1 loads), no barrier.
// Phase 2: wave owns 128-k slice; fixed-order two-round LDS reduce (w0+w2)+(w1+w3).
__global__ __launch_bounds__(256, 3) void k_ffn(
    const float* __restrict__ W1, const float* __restrict__ b1f,
    const float* __restrict__ W2, const float* __restrict__ g2,
    const float* __restrict__ b2, float* __restrict__ ws) {
  const int mtile = blockIdx.x >> 2;
  const int q = blockIdx.x & 3;
  const int r0 = mtile * 16;
  const int tid = threadIdx.x;
  const int wv = tid >> 6, lane = tid & 63;
  __shared__ __align__(16) float h2s[16][256];  // 16KB
  __shared__ __align__(16) float ts[16][512];   // 32KB; aliased as 2 reduce slabs

  // stage h2 = (x0 - mean) * rstd * g2 + b2, reconstructed from X0 + LNP
  {
    const float4* src = (const float4*)(ws + OFF_X0 + r0 * Dc);
    float4* dst = (float4*)&h2s[0][0];
#pragma unroll
    for (int k = 0; k < 4; ++k) {
      const int i4 = tid + k * 256;       // float4 index; 64 float4 per row
      const int r = i4 >> 6;
      const int dd = (i4 & 63) * 4;
      const float m = ws[OFF_LNP + (r0 + r) * 2 + 0];
      const float rstd = ws[OFF_LNP + (r0 + r) * 2 + 1];
      const float4 x = src[i4];
      const float4 gg = *(const float4*)&g2[dd];
      const float4 bb = *(const float4*)&b2[dd];
      float4 h;
      h.x = (x.x - m) * rstd * gg.x + bb.x;
      h.y = (x.y - m) * rstd * gg.y + bb.y;
      h.z = (x.z - m) * rstd * gg.z + bb.z;
      h.w = (x.w - m) * rstd * gg.w + bb.w;
      dst[i4] = h;
    }
  }
  __syncthreads();

  // ---- phase 1: T = relu(h2 @ W1[:, q] + b1f) ----
  const int rh = tid >> 7;        // 0: rows 0-7, 1: rows 8-15
  const int fl = (tid & 127) * 4; // local f in [0,512)
  const int fg = q * 512 + fl;    // global f
  float t[8][4];
  {
    const float4 bb = *(const float4*)&b1f[fg];
#pragma unroll
    for (int r = 0; r < 8; ++r) { t[r][0] = bb.x; t[r][1] = bb.y; t[r][2] = bb.z; t[r][3] = bb.w; }
  }
  for (int c = 0; c < Dc; c += 4) {
    float4 w1v[4];
#pragma unroll
    for (int k = 0; k < 4; ++k) w1v[k] = *(const float4*)&W1[(c + k) * Fc + fg];
#pragma unroll
    for (int r = 0; r < 8; ++r) {
      const float4 h = *(const float4*)&h2s[rh * 8 + r][c];
      const float hv[4] = {h.x, h.y, h.z, h.w};
#pragma unroll
      for (int k = 0; k < 4; ++k) {
        t[r][0] = fmaf(hv[k], w1v[k].x, t[r][0]);
        t[r][1] = fmaf(hv[k], w1v[k].y, t[r][1]);
        t[r][2] = fmaf(hv[k], w1v[k].z, t[r][2]);
        t[r][3] = fmaf(hv[k], w1v[k].w, t[r][3]);
      }
    }
  }
#pragma unroll
  for (int r = 0; r < 8; ++r) {
    float4 v;
    v.x = fmaxf(t[r][0], 0.f); v.y = fmaxf(t[r][1], 0.f);
    v.z = fmaxf(t[r][2], 0.f); v.w = fmaxf(t[r][3], 0.f);
    *(float4*)&ts[rh * 8 + r][fl] = v;
  }
  __syncthreads();

  // ---- phase 2: u = T @ W2[q]; wave wv owns local k-slice [wv*128, wv*128+128) ----
  const int d4 = lane * 4;
  float u[16][4];
#pragma unroll
  for (int r = 0; r < 16; ++r) { u[r][0] = 0.f; u[r][1] = 0.f; u[r][2] = 0.f; u[r][3] = 0.f; }
  for (int kk = 0; kk < 128; kk += 4) {
    const int kl = wv * 128 + kk;
    const int kg = q * 512 + kl;
    float4 w2v[4];
#pragma unroll
    for (int k = 0; k < 4; ++k) w2v[k] = *(const float4*)&W2[(kg + k) * Dc + d4];
#pragma unroll
    for (int r = 0; r < 16; ++r) {
      const float4 h = *(const float4*)&ts[r][kl];
      const float hv[4] = {h.x, h.y, h.z, h.w};
#pragma unroll
      for (int k = 0; k < 4; ++k) {
        u[r][0] = fmaf(hv[k], w2v[k].x, u[r][0]);
        u[r][1] = fmaf(hv[k], w2v[k].y, u[r][1]);
        u[r][2] = fmaf(hv[k], w2v[k].z, u[r][2]);
        u[r][3] = fmaf(hv[k], w2v[k].w, u[r][3]);
      }
    }
  }
  __syncthreads();  // all ts reads done before aliasing

  // ---- fixed-order reduce: slabA = w0+w2, slabB = w1+w3, out = A+B ----
  float* redb = &ts[0][0];  // 8192 floats: slabA [0,4096), slabB [4096,8192)
  if (wv < 2) {
    float* slab = redb + wv * 4096;
#pragma unroll
    for (int r = 0; r < 16; ++r) {
      float4 v; v.x = u[r][0]; v.y = u[r][1]; v.z = u[r][2]; v.w = u[r][3];
      *(float4*)&slab[r * 256 + d4] = v;
    }
  }
  __syncthreads();
  if (wv >= 2) {
    float* slab = redb + (wv - 2) * 4096;
#pragma unroll
    for (int r = 0; r < 16; ++r) {
      float4 p = *(float4*)&slab[r * 256 + d4];
      p.x += u[r][0]; p.y += u[r][1]; p.z += u[r][2]; p.w += u[r][3];
      *(float4*)&slab[r * 256 + d4] = p;
    }
  }
  __syncthreads();
  {
    const float4* A4 = (const float4*)redb;
    const float4* B4 = A4 + 1024;
    float4* up4 = (float4*)(ws + OFF_UP + q * SLAB + r0 * Dc);
#pragma unroll
    for (int k = 0; k < 4; ++k) {
      const int i4 = tid + k * 256;
      up4[i4] = f4add(A4[i4], B4[i4]);
    }
  }
}

// ---- K4: enc = x0 + U0..U3 + b2f (in place); z GEMV; fused lstar select ----
__global__ __launch_bounds__(256) void k_encz(
    const float* __restrict__ We1, const float* __restrict__ be1,
    const float* __restrict__ We2, const float* __restrict__ be2,
    const float* __restrict__ b2f, float* __restrict__ ws) {
  const int wg = blockIdx.x;  // b*T + i
  const int f = threadIdx.x;
  const int lane = f & 63, wv = f >> 6;
  __shared__ float encs[8][Dc];
  __shared__ __align__(16) float zred[8][4];
  __shared__ float zs[8];
  const float bb = b2f[f];
#pragma unroll
  for (int r = 0; r < 8; ++r) {
    const int row = wg * Lc + r;
    const float e = ((((ws[OFF_X0 + row * Dc + f] +
                        ws[OFF_UP + 0 * SLAB + row * Dc + f]) +
                       ws[OFF_UP + 1 * SLAB + row * Dc + f]) +
                      ws[OFF_UP + 2 * SLAB + row * Dc + f]) +
                     ws[OFF_UP + 3 * SLAB + row * Dc + f]) + bb;
    ws[OFF_ENC + row * Dc + f] = e;  // in place over X0
    encs[r][f] = e;
  }
  __syncthreads();

  float g[8];
  const float be1f = be1[f];
#pragma unroll
  for (int r = 0; r < 8; ++r) g[r] = be1f;
  for (int c = 0; c < Dc; ++c) {
    const float w = We1[c * Dc + f];
#pragma unroll
    for (int r = 0; r < 8; ++r) g[r] = fmaf(encs[r][c], w, g[r]);
  }
  const float w2 = We2[f];
#pragma unroll
  for (int r = 0; r < 8; ++r) {
    float p = fmaxf(g[r], 0.f) * w2;
#pragma unroll
    for (int off = 32; off; off >>= 1) p += __shfl_down(p, off, 64);
    if (lane == 0) zred[r][wv] = p;
  }
  __syncthreads();
  if (f < 8) {
    const float4 s4 = *(const float4*)zred[f];
    zs[f] = s4.x + s4.y + s4.z + s4.w + be2[0];
    ws[OFF_Z + wg * Lc + f] = zs[f];
  }
  __syncthreads();
  if (f == 0) {
    const int i = wg & (Tc - 1);
    const int lmax = imin(Tc - i, Lc);
    int ls = lmax;
    for (int l = 1; l <= lmax; ++l) {
      if (zs[l - 1] > 0.f) { ls = l; break; }
    }
    ((int*)(ws + OFF_LST))[wg] = ls;
  }
}

// ---- K5: sequential walk via wave shuffles + emit ----
__global__ __launch_bounds__(256) void k_emit(float* __restrict__ ws, float* __restrict__ out) {
  const int b = blockIdx.x;
  const int tid = threadIdx.x;
  __shared__ int lst[Tc];
  __shared__ int path[Tc];
  __shared__ int cnt_s;
  const int* lsrc = (const int*)(ws + OFF_LST);
  if (tid < Tc) lst[tid] = lsrc[b * Tc + tid];
  __syncthreads();
  if (tid < 64) {  // wave 0: walk via register shuffles
    const int a0 = lst[tid], a1 = lst[64 + tid];
    int cur = 0, s = 0;
    while (cur < Tc) {
      const int l = (cur < 64) ? __shfl(a0, cur, 64) : __shfl(a1, cur - 64, 64);
      if (tid == 0) path[s] = cur * Lc + l - 1;
      ++s;
      cur += l;
    }
    if (tid == 0) cnt_s = s;
  }
  __syncthreads();
  const int c = cnt_s;
  for (int s0 = 0; s0 < Tc; s0 += 8) {
    float v[8];
#pragma unroll
    for (int k = 0; k < 8; ++k) {
      const int s = s0 + k;
      v[k] = (s < c) ? ws[OFF_ENC + (b * Tc * Lc + path[s]) * Dc + tid] : 0.f;
    }
#pragma unroll
    for (int k = 0; k < 8; ++k) out[(b * Tc + s0 + k) * Dc + tid] = v[k];
  }
  if (tid == 0) out[Bc * Tc * Dc + b] = (float)c;
}

extern "C" void kernel_launch(void* const* d_in, const int* in_sizes, int n_in,
                              void* d_out, int out_size, void* d_ws, size_t ws_size,
                              hipStream_t stream) {
  const float* frames = (const float*)d_in[0];
  const float* cls    = (const float*)d_in[1];
  const float* Wq     = (const float*)d_in[2];
  const float* bq     = (const float*)d_in[3];
  const float* Wk     = (const float*)d_in[4];
  const float* bk     = (const float*)d_in[5];
  const float* Wv     = (const float*)d_in[6];
  const float* bv     = (const float*)d_in[7];
  const float* Wo     = (const float*)d_in[8];
  const float* bo     = (const float*)d_in[9];
  const float* g1     = (const float*)d_in[10];
  const float* b1     = (const float*)d_in[11];
  const float* g2     = (const float*)d_in[12];
  const float* b2     = (const float*)d_in[13];
  const float* W1     = (const float*)d_in[14];
  const float* b1f    = (const float*)d_in[15];
  const float* W2     = (const float*)d_in[16];
  const float* b2f    = (const float*)d_in[17];
  const float* We1    = (const float*)d_in[18];
  const float* be1    = (const float*)d_in[19];
  const float* We2    = (const float*)d_in[20];
  const float* be2    = (const float*)d_in[21];
  float* ws = (float*)d_ws;
  float* out = (float*)d_out;

  k_prep<<<Bc * Tc + 1, 256, 0, stream>>>(frames, cls, Wq, bq, Wk, bk, Wv, bv, Wo, g1, b1, ws);
  k_attn<<<Bc * Tc, 256, 0, stream>>>(cls, bo, ws);
  k_ffn<<<(NROWS / 16) * 4, 256, 0, stream>>>(W1, b1f, W2, g2, b2, ws);
  k_encz<<<Bc * Tc, 256, 0, stream>>>(We1, be1, We2, be2, b2f, ws);
  k_emit<<<Bc, 256, 0, stream>>>(ws, out);
}